// Round 9
// baseline (463.650 us; speedup 1.0000x reference)
//
#include <hip/hip_runtime.h>

#define TS 3584
#define VS 1792
#define TPF 448
#define NHEAD 12
#define HDIM 128
#define DMODEL 1536
// attention scale * log2(e), folded into q at rmsnorm; softmax uses exp2
#define QSCALE (0.08838834764831845f * 1.4426950408889634f)

typedef unsigned short u16;
typedef unsigned int u32;
typedef __attribute__((ext_vector_type(8))) short bf16x8;
typedef __attribute__((ext_vector_type(4))) float f32x4;

__device__ __forceinline__ float u2f(u32 u) { union { u32 u; float f; } c; c.u = u; return c.f; }
__device__ __forceinline__ u32 f2u(float f) { union { float f; u32 u; } c; c.f = f; return c.u; }
__device__ __forceinline__ float blo(u32 u) { return u2f(u << 16); }
__device__ __forceinline__ float bhi(u32 u) { return u2f(u & 0xffff0000u); }
__device__ __forceinline__ u16 f2b(float f) {
  u32 u = f2u(f);
  return (u16)((u + 0x7fffu + ((u >> 16) & 1u)) >> 16);
}

// Pack fp32 tensors to bf16 (RNE). z: 0=x, 1..3=q/k/v weights (concat), 4=o_w.
__global__ __launch_bounds__(256) void convert_bf16(
    const float* __restrict__ x, const float* __restrict__ qw,
    const float* __restrict__ kw, const float* __restrict__ vw,
    const float* __restrict__ ow, u16* __restrict__ xb,
    u16* __restrict__ wqkv, u16* __restrict__ owb) {
  const int z = blockIdx.y;
  const float* src;
  u16* dst;
  int n8;
  if (z == 0)      { src = x;  dst = xb;  n8 = TS * DMODEL / 8; }
  else if (z == 4) { src = ow; dst = owb; n8 = DMODEL * DMODEL / 8; }
  else {
    src = (z == 1) ? qw : (z == 2) ? kw : vw;
    dst = wqkv + (size_t)(z - 1) * DMODEL * DMODEL;
    n8 = DMODEL * DMODEL / 8;
  }
  const int idx = blockIdx.x * 256 + threadIdx.x;
  if (idx >= n8) return;
  const float4 a = ((const float4*)src)[2 * idx];
  const float4 b = ((const float4*)src)[2 * idx + 1];
  uint4 o;
  o.x = (u32)f2b(a.x) | ((u32)f2b(a.y) << 16);
  o.y = (u32)f2b(a.z) | ((u32)f2b(a.w) << 16);
  o.z = (u32)f2b(b.x) | ((u32)f2b(b.y) << 16);
  o.w = (u32)f2b(b.z) | ((u32)f2b(b.w) << 16);
  ((uint4*)dst)[idx] = o;
}

// MFMA NT GEMM (round-7 proven): C = A*W^T + bias. 128x128 tile, BK=64,
// 256 thr = 4 waves, wave = 64x64 via 4x4 mfma 16x16x32. XOR-swizzled LDS.
template <bool QKV>
__global__ __launch_bounds__(256) void gemm_mfma(
    const u16* __restrict__ A, const u16* __restrict__ W,
    const float* __restrict__ b0, const float* __restrict__ b1,
    const float* __restrict__ b2,
    u16* __restrict__ o0, u16* __restrict__ o1, u16* __restrict__ o2,
    float* __restrict__ of) {
  __shared__ __align__(16) u16 Als[128 * 64];
  __shared__ __align__(16) u16 Bls[128 * 64];
  const int t = threadIdx.x;
  const int wave = t >> 6, lane = t & 63, col = lane & 15, quad = lane >> 4;
  const int m0 = blockIdx.y * 128, n0 = blockIdx.x * 128;
  const int wm = (wave & 1) * 64, wn = (wave >> 1) * 64;
  f32x4 acc[4][4];
#pragma unroll
  for (int i = 0; i < 4; ++i)
#pragma unroll
    for (int j = 0; j < 4; ++j) acc[i][j] = (f32x4){0.f, 0.f, 0.f, 0.f};

  for (int k0 = 0; k0 < DMODEL; k0 += 64) {
    __syncthreads();
#pragma unroll
    for (int i = 0; i < 4; ++i) {
      const int idx = t + i * 256;
      const int row = idx >> 3, ch = idx & 7;
      *(uint4*)&Als[row * 64 + ((ch ^ (row & 7)) * 8)] =
          *(const uint4*)(A + (size_t)(m0 + row) * DMODEL + k0 + ch * 8);
      *(uint4*)&Bls[row * 64 + ((ch ^ (row & 7)) * 8)] =
          *(const uint4*)(W + (size_t)(n0 + row) * DMODEL + k0 + ch * 8);
    }
    __syncthreads();
#pragma unroll
    for (int s = 0; s < 2; ++s) {
      bf16x8 af[4], bv[4];
#pragma unroll
      for (int i = 0; i < 4; ++i) {
        const int r = wm + i * 16 + col;
        af[i] = *(const bf16x8*)&Als[r * 64 + (((s * 4 + quad) ^ (r & 7)) * 8)];
      }
#pragma unroll
      for (int j = 0; j < 4; ++j) {
        const int r = wn + j * 16 + col;
        bv[j] = *(const bf16x8*)&Bls[r * 64 + (((s * 4 + quad) ^ (r & 7)) * 8)];
      }
#pragma unroll
      for (int i = 0; i < 4; ++i)
#pragma unroll
        for (int j = 0; j < 4; ++j)
          acc[i][j] = __builtin_amdgcn_mfma_f32_16x16x32_bf16(af[i], bv[j], acc[i][j], 0, 0, 0);
    }
  }

#pragma unroll
  for (int j = 0; j < 4; ++j) {
    const int ng = n0 + wn + j * 16 + col;
    if constexpr (QKV) {
      const int sec = ng / DMODEL;       // block-uniform (128 | DMODEL)
      const int nn = ng - sec * DMODEL;
      u16* dst = sec == 0 ? o0 : (sec == 1 ? o1 : o2);
      const float bias = sec == 0 ? b0[nn] : (sec == 1 ? b1[nn] : b2[nn]);
#pragma unroll
      for (int i = 0; i < 4; ++i) {
        const int mb = m0 + wm + i * 16 + quad * 4;
#pragma unroll
        for (int r = 0; r < 4; ++r)
          dst[(size_t)(mb + r) * DMODEL + nn] = f2b(acc[i][j][r] + bias);
      }
    } else {
      const float bias = b0[ng];
#pragma unroll
      for (int i = 0; i < 4; ++i) {
        const int mb = m0 + wm + i * 16 + quad * 4;
#pragma unroll
        for (int r = 0; r < 4; ++r)
          of[(size_t)(mb + r) * DMODEL + ng] = acc[i][j][r] + bias;
      }
    }
  }
}

// In-place RMSNorm(+weight) then RoPE. y==0: q (also folds QSCALE for exp2 softmax).
__global__ __launch_bounds__(256) void rmsnorm_rope(
    u16* qbuf, u16* kbuf, const float* __restrict__ freqs,
    const float* __restrict__ nqw, const float* __restrict__ nkw) {
  const int tok = blockIdx.x;
  u32* row = (u32*)((blockIdx.y == 0 ? qbuf : kbuf) + (size_t)tok * DMODEL);
  const float* w = blockIdx.y == 0 ? nqw : nkw;
  const int t = threadIdx.x;
  const u32 u0 = row[t], u1 = row[t + 256], u2 = row[t + 512];
  float px[3] = { blo(u0), blo(u1), blo(u2) };
  float py[3] = { bhi(u0), bhi(u1), bhi(u2) };
  float ss = px[0] * px[0] + py[0] * py[0] + px[1] * px[1] + py[1] * py[1] +
             px[2] * px[2] + py[2] * py[2];
#pragma unroll
  for (int off = 32; off; off >>= 1) ss += __shfl_xor(ss, off);
  __shared__ float red[4];
  if ((t & 63) == 0) red[t >> 6] = ss;
  __syncthreads();
  float rstd = rsqrtf((red[0] + red[1] + red[2] + red[3]) * (1.0f / DMODEL) + 1e-6f);
  if (blockIdx.y == 0) rstd *= QSCALE;
  const int p = tok % VS;
  const int fi = p / TPF, rem = p % TPF, hi = rem / 28, wi = rem % 28;
#pragma unroll
  for (int jj = 0; jj < 3; ++jj) {
    const int pj = t + jj * 256;
    const int i = pj & 63;
    const int prow = (i < 22) ? fi : ((i < 43) ? hi : wi);
    const float ang = freqs[prow * 64 + i];
    float sn, cs;
    sincosf(ang, &sn, &cs);
    const float a = px[jj] * rstd * w[2 * pj], b = py[jj] * rstd * w[2 * pj + 1];
    row[pj] = (u32)f2b(a * cs - b * sn) | ((u32)f2b(a * sn + b * cs) << 16);
  }
}

// vt[h][hd][tok] = v[tok][h*128+hd]. 128-thread blocks; in-register 8x8 u16 transpose.
__global__ __launch_bounds__(128) void transpose_v(
    const u16* __restrict__ v, u16* __restrict__ vt) {
  __shared__ __align__(16) u16 T[128 * 128];
  const int h = blockIdx.y;
  const int t0 = blockIdx.x * 128;
  const int t = threadIdx.x;
#pragma unroll
  for (int i = 0; i < 16; ++i) {
    int idx = t + i * 128;
    int tok = idx >> 4, hd8 = idx & 15;
    *(uint4*)&T[tok * 128 + ((hd8 ^ (tok & 7)) * 8)] =
        *(const uint4*)(v + (size_t)(t0 + tok) * DMODEL + h * HDIM + hd8 * 8);
  }
  __syncthreads();
  const int hb = t >> 3;
#pragma unroll
  for (int half = 0; half < 2; ++half) {
    const int tb = (t & 7) + half * 8;
    uint4 M[8];
#pragma unroll
    for (int r = 0; r < 8; ++r)
      M[r] = *(const uint4*)&T[(tb * 8 + r) * 128 + ((hb ^ r) * 8)];
    uint4 O[8];
#pragma unroll
    for (int c2 = 0; c2 < 4; ++c2) {
      const u32* A = (const u32*)&M[2 * c2];
      const u32* Bp = (const u32*)&M[2 * c2 + 1];
#pragma unroll
      for (int jh = 0; jh < 4; ++jh) {
        u32 a = A[jh], b = Bp[jh];
        ((u32*)&O[2 * jh])[c2] = (a & 0xffffu) | (b << 16);
        ((u32*)&O[2 * jh + 1])[c2] = (a >> 16) | (b & 0xffff0000u);
      }
    }
#pragma unroll
    for (int j = 0; j < 8; ++j)
      *(uint4*)(vt + (size_t)(h * HDIM + hb * 8 + j) * TS + t0 + tb * 8) = O[j];
  }
}

// MFMA flash attention v3: union key set (in-view 1792 + cross-view same-frame 448).
// 2 waves x 32 queries (64q/block), BK=64, no-max exp2 softmax (logits bounded ~16),
// l computed from the same truncated-bf16 P as the numerator (bias cancels).
// Qls/Pls share one LDS buffer (Q dead after pre-loop frag load) -> 53 KB, 3 blk/CU.
// Grid 672, XCD-swizzled: all 28 q-blocks of one (head,view) land on one XCD.
__global__ __launch_bounds__(128) void attn_mfma(
    const u16* q, const u16* __restrict__ k,
    const u16* __restrict__ vt, u16* fused) {
  __shared__ __align__(16) u16 QP[64 * 136];        // Qls; later Pls[2][32*72]
  __shared__ __align__(16) u16 Kls[64 * 136];
  __shared__ __align__(16) u16 Vls[128 * 72];
  const int bid = blockIdx.x;
  const int xcd = bid & 7, slot = bid >> 3;
  const int combo = xcd * 3 + slot / 28;        // 24 (head,view) combos, 3 per XCD
  const int head = combo >> 1, vview = combo & 1;
  const int q0 = vview * VS + (slot % 28) * 64;
  const int fidx = (q0 % VS) / TPF;
  const int t = threadIdx.x;
  const int wave = t >> 6, lane = t & 63;
  const int col = lane & 15, quad = lane >> 4;
  u16* Pls = QP + wave * 2304;                  // 32 rows x 72 u16, wave-private

  // stage Q (64 x 128): 1024 uint4, 8 per thread
#pragma unroll
  for (int i = 0; i < 8; ++i) {
    int idx = t + i * 128;
    int row = idx >> 4, ch = idx & 15;
    *(uint4*)&QP[row * 136 + ch * 8] =
        *(const uint4*)(q + (size_t)(q0 + row) * DMODEL + head * HDIM + ch * 8);
  }
  __syncthreads();
  bf16x8 qfrag[2][4];
#pragma unroll
  for (int qg = 0; qg < 2; ++qg)
#pragma unroll
    for (int c = 0; c < 4; ++c)
      qfrag[qg][c] =
          *(const bf16x8*)&QP[(wave * 32 + qg * 16 + col) * 136 + (c * 4 + quad) * 8];

  f32x4 accO[2][8];
#pragma unroll
  for (int qg = 0; qg < 2; ++qg)
#pragma unroll
    for (int c = 0; c < 8; ++c) accO[qg][c] = (f32x4){0.f, 0.f, 0.f, 0.f};
  float l_part[2] = {0.f, 0.f};

  const int base0 = vview * VS;
  const int base1 = (1 - vview) * VS + fidx * TPF;

  for (int it = 0; it < 35; ++it) {
    const int base = (it < 28) ? (base0 + it * 64) : (base1 + (it - 28) * 64);
    __syncthreads();
    // stage K (64 keys x 128 hd) + V (128 hd x 64 keys), 8+8 uint4 per thread
#pragma unroll
    for (int i = 0; i < 8; ++i) {
      int idx = t + i * 128;
      int row = idx >> 4, ch = idx & 15;
      *(uint4*)&Kls[row * 136 + ch * 8] =
          *(const uint4*)(k + (size_t)(base + row) * DMODEL + head * HDIM + ch * 8);
      int vrow = idx >> 3, vch = idx & 7;
      *(uint4*)&Vls[vrow * 72 + vch * 8] =
          *(const uint4*)(vt + (size_t)(head * HDIM + vrow) * TS + base + vch * 8);
    }
    __syncthreads();

    // S^T = K*Q^T : 4 key-groups x 2 q-groups (col = query)
    f32x4 s[2][4];
#pragma unroll
    for (int qg = 0; qg < 2; ++qg)
#pragma unroll
      for (int g = 0; g < 4; ++g) s[qg][g] = (f32x4){0.f, 0.f, 0.f, 0.f};
#pragma unroll
    for (int c = 0; c < 4; ++c) {
      bf16x8 ka[4];
#pragma unroll
      for (int g = 0; g < 4; ++g)
        ka[g] = *(const bf16x8*)&Kls[(g * 16 + col) * 136 + (c * 4 + quad) * 8];
#pragma unroll
      for (int qg = 0; qg < 2; ++qg)
#pragma unroll
        for (int g = 0; g < 4; ++g)
          s[qg][g] = __builtin_amdgcn_mfma_f32_16x16x32_bf16(ka[g], qfrag[qg][c], s[qg][g], 0, 0, 0);
    }

    // no-max softmax: p = exp2(s); truncate to bf16; l from the same truncated p
#pragma unroll
    for (int qg = 0; qg < 2; ++qg) {
#pragma unroll
      for (int g = 0; g < 4; ++g) {
        float pt[4];
#pragma unroll
        for (int r = 0; r < 4; ++r) {
          float p = __builtin_amdgcn_exp2f(s[qg][g][r]);
          pt[r] = u2f(f2u(p) & 0xffff0000u);
          l_part[qg] += pt[r];
        }
        u32 lo = (f2u(pt[0]) >> 16) | (f2u(pt[1]) & 0xffff0000u);
        u32 hi = (f2u(pt[2]) >> 16) | (f2u(pt[3]) & 0xffff0000u);
        *(uint2*)&Pls[(qg * 16 + col) * 72 + g * 16 + quad * 4] = make_uint2(lo, hi);
      }
    }
    asm volatile("s_waitcnt lgkmcnt(0)" ::: "memory");  // wave-private P round-trip

    bf16x8 pf[2][2];
#pragma unroll
    for (int qg = 0; qg < 2; ++qg) {
      pf[qg][0] = *(const bf16x8*)&Pls[(qg * 16 + col) * 72 + quad * 8];
      pf[qg][1] = *(const bf16x8*)&Pls[(qg * 16 + col) * 72 + 32 + quad * 8];
    }
    // O^T += Vt*P : va reads shared across both q-groups
#pragma unroll
    for (int c = 0; c < 8; ++c) {
      bf16x8 va0 = *(const bf16x8*)&Vls[(c * 16 + col) * 72 + quad * 8];
      bf16x8 va1 = *(const bf16x8*)&Vls[(c * 16 + col) * 72 + 32 + quad * 8];
#pragma unroll
      for (int qg = 0; qg < 2; ++qg) {
        accO[qg][c] = __builtin_amdgcn_mfma_f32_16x16x32_bf16(va0, pf[qg][0], accO[qg][c], 0, 0, 0);
        accO[qg][c] = __builtin_amdgcn_mfma_f32_16x16x32_bf16(va1, pf[qg][1], accO[qg][c], 0, 0, 0);
      }
    }
  }

#pragma unroll
  for (int qg = 0; qg < 2; ++qg) {
    float l = l_part[qg];
    l += __shfl_xor(l, 16);
    l += __shfl_xor(l, 32);
    const float inv = 1.0f / l;
    const int token = q0 + wave * 32 + qg * 16 + col;
    u16* orow = fused + (size_t)token * DMODEL + head * HDIM;
#pragma unroll
    for (int c = 0; c < 8; ++c) {
      u32 a = (u32)f2b(accO[qg][c][0] * inv) | ((u32)f2b(accO[qg][c][1] * inv) << 16);
      u32 b = (u32)f2b(accO[qg][c][2] * inv) | ((u32)f2b(accO[qg][c][3] * inv) << 16);
      *(u32*)(orow + c * 16 + quad * 4) = a;
      *(u32*)(orow + c * 16 + quad * 4 + 2) = b;
    }
  }
}

extern "C" void kernel_launch(void* const* d_in, const int* in_sizes, int n_in,
                              void* d_out, int out_size, void* d_ws, size_t ws_size,
                              hipStream_t stream) {
  (void)in_sizes; (void)n_in; (void)out_size; (void)ws_size;
  const float* x   = (const float*)d_in[0];
  const float* fr  = (const float*)d_in[1];
  const float* qw  = (const float*)d_in[2];
  const float* qb  = (const float*)d_in[3];
  const float* kw  = (const float*)d_in[4];
  const float* kb  = (const float*)d_in[5];
  const float* vw  = (const float*)d_in[6];
  const float* vb  = (const float*)d_in[7];
  const float* ow  = (const float*)d_in[8];
  const float* ob  = (const float*)d_in[9];
  const float* nqw = (const float*)d_in[10];
  const float* nkw = (const float*)d_in[11];

  // ws (bf16): qf(->fused) | vf | xb | wqkv(3x1536^2) | owb (~52 MB).
  // d_out (fp32, 22 MB) dead until gemm_out: kf lower 11 MB, vtb upper 11 MB.
  u16* qf   = (u16*)d_ws;
  u16* vf   = qf + (size_t)TS * DMODEL;
  u16* xb   = vf + (size_t)TS * DMODEL;
  u16* wqkv = xb + (size_t)TS * DMODEL;
  u16* owb  = wqkv + (size_t)3 * DMODEL * DMODEL;
  u16* kf   = (u16*)d_out;
  u16* vtb  = (u16*)d_out + (size_t)TS * DMODEL;

  convert_bf16<<<dim3(TS * DMODEL / 8 / 256, 5), dim3(256), 0, stream>>>(
      x, qw, kw, vw, ow, xb, wqkv, owb);
  gemm_mfma<true><<<dim3(3 * DMODEL / 128, TS / 128), dim3(256), 0, stream>>>(
      xb, wqkv, qb, kb, vb, qf, kf, vf, nullptr);
  rmsnorm_rope<<<dim3(TS, 2), dim3(256), 0, stream>>>(qf, kf, fr, nqw, nkw);
  transpose_v<<<dim3(TS / 128, NHEAD), dim3(128), 0, stream>>>(vf, vtb);
  attn_mfma<<<dim3(672), dim3(128), 0, stream>>>(qf, kf, vtb, qf);
  gemm_mfma<false><<<dim3(DMODEL / 128, TS / 128), dim3(256), 0, stream>>>(
      qf, owb, ob, nullptr, nullptr, nullptr, nullptr, nullptr, (float*)d_out);
}